// Round 11
// baseline (440.957 us; speedup 1.0000x reference)
//
#include <hip/hip_runtime.h>
#include <hip/hip_bf16.h>
#include <math.h>

// All reference tensors are jnp.float32. GEMMs run in pure bf16 (fp32 acc).

#define B_ 2
#define L_ 2048
#define DM_ 1024
#define DI_ 2048
#define NS_ 16
#define DTR_ 128
#define XPN_ 160   // DTR + 2*NS
#define CH_ 32     // chunks over L
#define CL_ 64     // L / CH_
#define NCH_ 4096  // B_ * DI_
#define SK_ 8      // GEMM2 split-K factor (round-8 known-good)

typedef __attribute__((ext_vector_type(8))) short short8;
typedef __attribute__((ext_vector_type(4))) float f32x4;

__device__ inline unsigned short bfbits(float f) {
    __hip_bfloat16 h = __float2bfloat16(f);
    return *reinterpret_cast<unsigned short*>(&h);
}

// ---------------- fused pair cast: fp32 -> bf16 (two equal-size arrays) ----
__global__ __launch_bounds__(256) void cast_pair(
    const float* __restrict__ s0, unsigned short* __restrict__ d0,
    const float* __restrict__ s1, unsigned short* __restrict__ d1, int nper)
{
    int i = (blockIdx.x * 256 + threadIdx.x) * 4;
    const float* s = s0;
    unsigned short* d = d0;
    if (i >= nper) { s = s1; d = d1; i -= nper; }
    float4 v = *(const float4*)(s + i);
    *(ushort4*)(d + i) = make_ushort4(bfbits(v.x), bfbits(v.y), bfbits(v.z), bfbits(v.w));
}

// -------- fused cast: y (strided out of XZ) + out_proj (flat) -> bf16 -----
__global__ __launch_bounds__(256) void cast_y_op(
    const float* __restrict__ XZ, unsigned short* __restrict__ yb,
    const float* __restrict__ op, unsigned short* __restrict__ ob, int ny4)
{
    int idx = blockIdx.x * 256 + threadIdx.x;
    if (idx < ny4) {                              // y: cols 0..DI-1 of XZ
        int t = idx >> 9;                         // DI_/4 = 512
        int d = (idx & 511) * 4;
        float4 v = *(const float4*)(XZ + (long)t * (2 * DI_) + d);
        long off = (long)t * DI_ + d;
        *(ushort4*)(yb + off) = make_ushort4(bfbits(v.x), bfbits(v.y), bfbits(v.z), bfbits(v.w));
    } else {                                      // out_proj flat
        int i = (idx - ny4) * 4;
        float4 v = *(const float4*)(op + i);
        *(ushort4*)(ob + i) = make_ushort4(bfbits(v.x), bfbits(v.y), bfbits(v.z), bfbits(v.w));
    }
}

// ---------------- MFMA bf16 GEMM (pre-cast inputs): C = A @ B^T ----------
// 128x128 block, 4 waves, each wave 64x64 = 4x4 tiles of 16x16, KT=32.
// Fragment-major LDS, identity staging: unit g = tid (+c*256) holds global
// element (row = (g>>6)*16 + (g&15), k-octet = (g>>4)&3). Stores AND reads
// are both 64-consecutive-16B-units per wave (bank-minimal); the per-wave
// global address set (16 rows x 64B) is unchanged vs row-major staging.
__global__ __launch_bounds__(256) void gemm_mfma(
    const unsigned short* __restrict__ A, int lda,
    const unsigned short* __restrict__ B, int ldb,
    float* __restrict__ C, int ldc, int K)
{
    __shared__ unsigned short sA[128 * 32];
    __shared__ unsigned short sB[128 * 32];
    const int tid = threadIdx.x;
    const int lane = tid & 63, wave = tid >> 6;
    const int row0 = blockIdx.y * 128, col0 = blockIdx.x * 128;
    const int wm = (wave & 1) << 6, wn = (wave >> 1) << 6;
    const int m = lane & 15;
    const int wa = (wave & 1) << 2;   // A rb base = wm>>4
    const int wb = (wave >> 1) << 2;  // B rb base = wn>>4

    f32x4 acc[4][4];
    const f32x4 zero = {0.f, 0.f, 0.f, 0.f};
#pragma unroll
    for (int i = 0; i < 4; ++i)
#pragma unroll
        for (int j = 0; j < 4; ++j) acc[i][j] = zero;

    for (int k0 = 0; k0 < K; k0 += 32) {
#pragma unroll
        for (int c = 0; c < 2; ++c) {
            int g = tid + (c << 8);            // 0..511 = LDS 16B-unit index
            int rm = g & 15;
            int cq = (g >> 4) & 3;             // k-octet
            int r = ((g >> 6) << 4) + rm;      // row 0..127
            *(short8*)&sA[g * 8] = *(const short8*)(A + (long)(row0 + r) * lda + k0 + (cq << 3));
            *(short8*)&sB[g * 8] = *(const short8*)(B + (long)(col0 + r) * ldb + k0 + (cq << 3));
        }
        __syncthreads();

        short8 af[4];
#pragma unroll
        for (int i = 0; i < 4; ++i)
            af[i] = *(const short8*)&sA[((wa + i) * 64 + lane) * 8];
#pragma unroll
        for (int j = 0; j < 4; ++j) {
            short8 bf = *(const short8*)&sB[((wb + j) * 64 + lane) * 8];
#pragma unroll
            for (int i = 0; i < 4; ++i)
                acc[i][j] = __builtin_amdgcn_mfma_f32_16x16x32_bf16(af[i], bf, acc[i][j], 0, 0, 0);
        }
        __syncthreads();
    }

    const int cr = (lane >> 4) << 2;
#pragma unroll
    for (int i = 0; i < 4; ++i) {
#pragma unroll
        for (int j = 0; j < 4; ++j) {
            int gr = row0 + wm + i * 16 + cr;
            int gc = col0 + wn + j * 16 + m;
#pragma unroll
            for (int r = 0; r < 4; ++r)
                C[(long)(gr + r) * ldc + gc] = acc[i][j][r];
        }
    }
}

// ------- 64x64-tile bf16 GEMM, fragment-major LDS, identity staging -------
// 256 threads = 4 waves; wave w: rows [w*16, w*16+16) x 64 cols.
__global__ __launch_bounds__(256) void gemm_b64(
    const unsigned short* __restrict__ A, int lda,
    const unsigned short* __restrict__ B, int ldb,
    float* __restrict__ C, int ldc, int K)
{
    __shared__ unsigned short sA[64 * 32];
    __shared__ unsigned short sB[64 * 32];
    const int tid = threadIdx.x;
    const int lane = tid & 63, wave = tid >> 6;
    const int row0 = blockIdx.y * 64, col0 = blockIdx.x * 64;
    const int m = lane & 15;

    f32x4 acc[4];
    const f32x4 zero = {0.f, 0.f, 0.f, 0.f};
#pragma unroll
    for (int j = 0; j < 4; ++j) acc[j] = zero;

    for (int k0 = 0; k0 < K; k0 += 32) {
        int g = tid;                        // 0..255 = LDS 16B-unit index
        int rm = g & 15;
        int cq = (g >> 4) & 3;
        int r = ((g >> 6) << 4) + rm;       // row 0..63
        *(short8*)&sA[g * 8] = *(const short8*)(A + (long)(row0 + r) * lda + k0 + (cq << 3));
        *(short8*)&sB[g * 8] = *(const short8*)(B + (long)(col0 + r) * ldb + k0 + (cq << 3));
        __syncthreads();

        short8 af = *(const short8*)&sA[(wave * 64 + lane) * 8];
#pragma unroll
        for (int j = 0; j < 4; ++j) {
            short8 bf = *(const short8*)&sB[(j * 64 + lane) * 8];
            acc[j] = __builtin_amdgcn_mfma_f32_16x16x32_bf16(af, bf, acc[j], 0, 0, 0);
        }
        __syncthreads();
    }

    const int cr = (lane >> 4) << 2;
    const int gr = row0 + (wave << 4) + cr;
#pragma unroll
    for (int j = 0; j < 4; ++j) {
        int gc = col0 + j * 16 + m;
#pragma unroll
        for (int r = 0; r < 4; ++r)
            C[(long)(gr + r) * ldc + gc] = acc[j][r];
    }
}

// ------- small-K MFMA GEMM, 64x64 tiles, fp32 inputs cast on the fly ------
enum { ME_PART = 0, ME_SOFTPLUS = 1 };

template <int EPI>
__global__ __launch_bounds__(256) void gemm_s64(
    const float* __restrict__ A, int lda,
    const float* __restrict__ B, int ldb,
    float* __restrict__ C, int ldc,
    const float* __restrict__ bias,
    int N, int kslice, long partStride)
{
    __shared__ unsigned short sA[64][40];
    __shared__ unsigned short sB[64][40];
    const int tid = threadIdx.x;
    const int lane = tid & 63, wave = tid >> 6;
    const int row0 = blockIdx.y * 64, col0 = blockIdx.x * 64;
    const int m = lane & 15;
    const int ko = (lane >> 4) << 3;
    const int kbeg = blockIdx.z * kslice;
    const int kend = kbeg + kslice;

    f32x4 acc[4];
    const f32x4 zero = {0.f, 0.f, 0.f, 0.f};
#pragma unroll
    for (int j = 0; j < 4; ++j) acc[j] = zero;

    for (int k0 = kbeg; k0 < kend; k0 += 32) {
#pragma unroll
        for (int c = 0; c < 2; ++c) {
            int idx = tid + (c << 8);         // 0..511
            int r = idx >> 3;                 // 0..63
            int c4 = (idx & 7) << 2;          // 0,4,..,28
            float4 v = *(const float4*)(A + (long)(row0 + r) * lda + k0 + c4);
            *(ushort4*)&sA[r][c4] = make_ushort4(bfbits(v.x), bfbits(v.y), bfbits(v.z), bfbits(v.w));
            int gr = col0 + r;
            float4 w = make_float4(0.f, 0.f, 0.f, 0.f);
            if (gr < N) w = *(const float4*)(B + (long)gr * ldb + k0 + c4);
            *(ushort4*)&sB[r][c4] = make_ushort4(bfbits(w.x), bfbits(w.y), bfbits(w.z), bfbits(w.w));
        }
        __syncthreads();

        short8 af = *(const short8*)&sA[(wave << 4) + m][ko];
#pragma unroll
        for (int j = 0; j < 4; ++j) {
            short8 bf = *(const short8*)&sB[j * 16 + m][ko];
            acc[j] = __builtin_amdgcn_mfma_f32_16x16x32_bf16(af, bf, acc[j], 0, 0, 0);
        }
        __syncthreads();
    }

    const int cr = (lane >> 4) << 2;
    const int gr = row0 + (wave << 4) + cr;
    float* Cp = C + (long)blockIdx.z * partStride;
#pragma unroll
    for (int j = 0; j < 4; ++j) {
        int gc = col0 + j * 16 + m;
        if (gc >= N) continue;
#pragma unroll
        for (int r = 0; r < 4; ++r) {
            float v = acc[j][r];
            if (EPI == ME_SOFTPLUS) {
                v += bias[gc];
                v = (v > 20.f) ? v : log1pf(__expf(v));
            }
            Cp[(long)(gr + r) * ldc + gc] = v;
        }
    }
}

// ---------------- split-K partial reduction: O = sum_s P[s] ----------------
__global__ __launch_bounds__(256) void reduce_part(
    const float* __restrict__ P, float* __restrict__ O, int n)
{
    int i = (blockIdx.x * 256 + threadIdx.x) * 4;
    if (i >= n) return;
    float4 s = *(const float4*)(P + i);
#pragma unroll
    for (int k = 1; k < SK_; ++k) {
        float4 v = *(const float4*)(P + (long)k * n + i);
        s.x += v.x; s.y += v.y; s.z += v.z; s.w += v.w;
    }
    *(float4*)(O + i) = s;
}

// ---------------- causal depthwise conv(4) + bias + SiLU ----------------
__global__ __launch_bounds__(256) void conv_silu(
    const float* __restrict__ xz, const float* __restrict__ w,
    const float* __restrict__ bc, float* __restrict__ U)
{
    int idx = blockIdx.x * 256 + threadIdx.x;       // (b*L + t)*DI + d
    if (idx >= B_ * L_ * DI_) return;
    int d = idx & (DI_ - 1);
    int bt = idx >> 11;
    int t = bt & (L_ - 1);
    float s = bc[d];
#pragma unroll
    for (int j = 0; j < 4; ++j) {
        int tt = t - 3 + j;
        if (tt >= 0)
            s += w[d * 4 + j] * xz[((long)(bt - t + tt)) * (2 * DI_) + d];
    }
    U[idx] = s / (1.f + __expf(-s));                // silu
}

// ---------------- Pass A: per-chunk h_end + dt-sum only --------------------
__global__ __launch_bounds__(256) void scan_head(
    const float* __restrict__ U, const float* __restrict__ DT,
    const float* __restrict__ XDBL, const float* __restrict__ A_log,
    float* __restrict__ HEND, float* __restrict__ SDT)
{
    const int d = blockIdx.x * 256 + threadIdx.x;
    const int chunk = blockIdx.y;
    const int b = blockIdx.z;
    const int channel = b * DI_ + d;
    const long t0 = (long)b * L_ + chunk * CL_;

    float An[NS_], h[NS_];
#pragma unroll
    for (int n = 0; n < NS_; ++n) {
        An[n] = -__expf(A_log[d * NS_ + n]);
        h[n] = 0.f;
    }
    float sum_dt = 0.f;
    __shared__ float sB[8][NS_];

    for (int tt0 = 0; tt0 < CL_; tt0 += 8) {
        const long bt0 = t0 + tt0;
        if (threadIdx.x < 128) {
            int i = threadIdx.x >> 4, j = threadIdx.x & 15;
            sB[i][j] = XDBL[(bt0 + i) * XPN_ + DTR_ + j];
        }
        __syncthreads();
        float u8[8], dt8[8];
#pragma unroll
        for (int i = 0; i < 8; ++i) u8[i] = U[(bt0 + i) * DI_ + d];
#pragma unroll
        for (int i = 0; i < 8; ++i) dt8[i] = DT[(bt0 + i) * DI_ + d];
#pragma unroll
        for (int i = 0; i < 8; ++i) {
            const float dt = dt8[i];
            sum_dt += dt;
            const float du = dt * u8[i];
#pragma unroll
            for (int n = 0; n < NS_; ++n)
                h[n] = __expf(An[n] * dt) * h[n] + du * sB[i][n];
        }
        __syncthreads();
    }
#pragma unroll
    for (int n = 0; n < NS_; ++n)
        HEND[(chunk * NS_ + n) * NCH_ + channel] = h[n];
    SDT[chunk * NCH_ + channel] = sum_dt;
}

// ---------------- Pass B: combine chunk states (in-place) ----------------
__global__ __launch_bounds__(256) void scan_mid(
    const float* __restrict__ SDT, const float* __restrict__ A_log,
    float* __restrict__ HST)
{
    const int channel = blockIdx.x * 256 + threadIdx.x;
    const int d = channel & (DI_ - 1);
    float An[NS_], h0[NS_];
#pragma unroll
    for (int n = 0; n < NS_; ++n) {
        An[n] = -__expf(A_log[d * NS_ + n]);
        h0[n] = 0.f;
    }
    for (int c = 0; c < CH_; ++c) {
        float he[NS_];
#pragma unroll
        for (int n = 0; n < NS_; ++n) {
            he[n] = HST[(c * NS_ + n) * NCH_ + channel];
            HST[(c * NS_ + n) * NCH_ + channel] = h0[n];
        }
        if (c < CH_ - 1) {
            const float S = SDT[c * NCH_ + channel];
#pragma unroll
            for (int n = 0; n < NS_; ++n)
                h0[n] = __expf(An[n] * S) * h0[n] + he[n];
        }
    }
}

// ---------------- Pass C: full recurrence from h_start + gate --------------
__global__ __launch_bounds__(256) void scan_tail(
    const float* __restrict__ U, const float* __restrict__ DT,
    const float* __restrict__ XDBL, const float* __restrict__ A_log,
    const float* __restrict__ Dp, const float* __restrict__ HST,
    float* __restrict__ XZ)
{
    const int d = blockIdx.x * 256 + threadIdx.x;
    const int chunk = blockIdx.y;
    const int b = blockIdx.z;
    const int channel = b * DI_ + d;
    const long t0 = (long)b * L_ + chunk * CL_;

    float An[NS_], h[NS_];
#pragma unroll
    for (int n = 0; n < NS_; ++n) {
        An[n] = -__expf(A_log[d * NS_ + n]);
        h[n] = HST[(chunk * NS_ + n) * NCH_ + channel];
    }
    const float Dd = Dp[d];
    __shared__ float sB[8][NS_], sC[8][NS_];

    for (int tt0 = 0; tt0 < CL_; tt0 += 8) {
        const long bt0 = t0 + tt0;
        {
            int i = threadIdx.x >> 5, j = threadIdx.x & 31;
            float v = XDBL[(bt0 + i) * XPN_ + DTR_ + j];
            if (j < NS_) sB[i][j] = v; else sC[i][j - NS_] = v;
        }
        __syncthreads();
        float u8[8], dt8[8], z8[8], y8[8];
#pragma unroll
        for (int i = 0; i < 8; ++i) u8[i] = U[(bt0 + i) * DI_ + d];
#pragma unroll
        for (int i = 0; i < 8; ++i) dt8[i] = DT[(bt0 + i) * DI_ + d];
#pragma unroll
        for (int i = 0; i < 8; ++i) z8[i] = XZ[(bt0 + i) * (2 * DI_) + DI_ + d];
#pragma unroll
        for (int i = 0; i < 8; ++i) {
            const float dt = dt8[i];
            const float du = dt * u8[i];
            float y = 0.f;
#pragma unroll
            for (int n = 0; n < NS_; ++n) {
                h[n] = __expf(An[n] * dt) * h[n] + du * sB[i][n];
                y += h[n] * sC[i][n];
            }
            y += u8[i] * Dd;
            const float z = z8[i];
            y8[i] = y * (z / (1.f + __expf(-z)));
        }
#pragma unroll
        for (int i = 0; i < 8; ++i) XZ[(bt0 + i) * (2 * DI_) + d] = y8[i];
        __syncthreads();
    }
}

extern "C" void kernel_launch(void* const* d_in, const int* in_sizes, int n_in,
                              void* d_out, int out_size, void* d_ws, size_t ws_size,
                              hipStream_t stream)
{
    const float* x        = (const float*)d_in[0];
    const float* in_proj  = (const float*)d_in[1];
    const float* conv_w   = (const float*)d_in[2];
    const float* conv_b   = (const float*)d_in[3];
    const float* x_proj   = (const float*)d_in[4];
    const float* dt_proj  = (const float*)d_in[5];
    const float* dt_projb = (const float*)d_in[6];
    const float* A_log    = (const float*)d_in[7];
    const float* Dp       = (const float*)d_in[8];
    const float* out_proj = (const float*)d_in[9];

    const int M = B_ * L_;                       // 4096
    float* XZ   = (float*)d_ws;                  // [M, 2*DI]   67 MB
    float* U    = XZ + (size_t)M * 2 * DI_;      // [M, DI]     33.5 MB
    float* XDBL = U + (size_t)M * DI_;           // [M, 160]    2.6 MB
    float* DT   = XDBL + (size_t)M * XPN_;       // [M, DI]     33.5 MB
    float* SDT  = DT + (size_t)M * DI_;          // [CH][NCH]   0.5 MB
    float* HEND = (float*)d_out;                 // 8.4 MB in d_out (dead until GEMM4)

    // --- overlays (disjoint lifetimes) ---
    const int NX = M * DM_;
    const int NO = DM_ * DI_;
    unsigned short* XB = (unsigned short*)U;          // x bf16; dead before conv writes U
    unsigned short* WB = (unsigned short*)DT;         // in_proj bf16; dead after GEMM1
    float* PART = DT;                                 // [SK_][M][160] = 21 MB, dead after reduce
    unsigned short* YB = (unsigned short*)U;          // y bf16; U dead after scan_tail
    unsigned short* OB = (unsigned short*)DT;         // out_proj bf16; DT dead after scan_tail

    // 1) cast x and in_proj to bf16 (single fused launch)
    cast_pair<<<2 * NX / 1024, 256, 0, stream>>>(x, XB, in_proj, WB, NX);

    // 2) xz = x @ in_proj^T  (MFMA bf16, fragment-major LDS)  [4096 x 4096]
    gemm_mfma<<<dim3(32, 32), 256, 0, stream>>>(
        XB, DM_, WB, DM_, XZ, 2 * DI_, DM_);

    // 3) u = silu(conv(xb) + b)
    conv_silu<<<(M * DI_ + 255) / 256, 256, 0, stream>>>(XZ, conv_w, conv_b, U);

    // 4) x_dbl = u @ x_proj^T  [4096 x 160], K=2048; split-K x8, 64x64 tiles
    gemm_s64<ME_PART><<<dim3(3, 64, SK_), 256, 0, stream>>>(
        U, DI_, x_proj, DI_, PART, XPN_, nullptr, XPN_, 2048 / SK_, (long)M * XPN_);
    reduce_part<<<(M * XPN_) / 1024, 256, 0, stream>>>(PART, XDBL, M * XPN_);

    // 5) dt = softplus(x_dbl[:, :128] @ dt_proj^T + b)  [4096 x 2048], K=128
    gemm_s64<ME_SOFTPLUS><<<dim3(32, 64, 1), 256, 0, stream>>>(
        XDBL, XPN_, dt_proj, DTR_, DT, DI_, dt_projb, DI_, DTR_, 0);

    // 6) chunked selective scan
    scan_head<<<dim3(8, CH_, B_), 256, 0, stream>>>(U, DT, XDBL, A_log, HEND, SDT);
    scan_mid<<<NCH_ / 256, 256, 0, stream>>>(SDT, A_log, HEND);
    scan_tail<<<dim3(8, CH_, B_), 256, 0, stream>>>(U, DT, XDBL, A_log, Dp, HEND, XZ);

    // 7) cast y + out_proj to bf16 (single fused launch)
    cast_y_op<<<(M * DI_ / 4 + NO / 4) / 256, 256, 0, stream>>>(
        XZ, YB, out_proj, OB, M * DI_ / 4);

    // 8) out = y @ out_proj^T  (64x64 bf16, fragment-major LDS)  [4096 x 1024]
    gemm_b64<<<dim3(16, 64), 256, 0, stream>>>(
        YB, DI_, OB, DI_, (float*)d_out, DM_, DI_);
}

// Round 12
// 394.418 us; speedup vs baseline: 1.1180x; 1.1180x over previous
//
#include <hip/hip_runtime.h>
#include <hip/hip_bf16.h>
#include <math.h>

// All reference tensors are jnp.float32. GEMMs run in pure bf16 (fp32 acc).
// NOTE (r10/r11 post-mortem): row-major [.][40] LDS staging is the proven
// layout. SQ_LDS_BANK_CONFLICT on b128 is NOT a stall counter here; the
// "conflict-free" fragment-major layouts regressed via quarter-wave global
// scatter (r11) / store conflicts (r10). Do not revisit.

#define B_ 2
#define L_ 2048
#define DM_ 1024
#define DI_ 2048
#define NS_ 16
#define DTR_ 128
#define XPN_ 160   // DTR + 2*NS
#define CH_ 32     // chunks over L
#define CL_ 64     // L / CH_
#define NCH_ 4096  // B_ * DI_
#define SK_ 8      // GEMM2 split-K factor (round-8 known-good)

typedef __attribute__((ext_vector_type(8))) short short8;
typedef __attribute__((ext_vector_type(4))) float f32x4;

__device__ inline unsigned short bfbits(float f) {
    __hip_bfloat16 h = __float2bfloat16(f);
    return *reinterpret_cast<unsigned short*>(&h);
}

// ---------------- fused pair cast: fp32 -> bf16 (two equal-size arrays) ----
__global__ __launch_bounds__(256) void cast_pair(
    const float* __restrict__ s0, unsigned short* __restrict__ d0,
    const float* __restrict__ s1, unsigned short* __restrict__ d1, int nper)
{
    int i = (blockIdx.x * 256 + threadIdx.x) * 4;
    const float* s = s0;
    unsigned short* d = d0;
    if (i >= nper) { s = s1; d = d1; i -= nper; }
    float4 v = *(const float4*)(s + i);
    *(ushort4*)(d + i) = make_ushort4(bfbits(v.x), bfbits(v.y), bfbits(v.z), bfbits(v.w));
}

// ---------------- flat cast: fp32 -> bf16 ----------------
__global__ __launch_bounds__(256) void cast_flat(
    const float* __restrict__ s, unsigned short* __restrict__ o, int n)
{
    int i = (blockIdx.x * 256 + threadIdx.x) * 4;
    if (i >= n) return;
    float4 v = *(const float4*)(s + i);
    *(ushort4*)(o + i) = make_ushort4(bfbits(v.x), bfbits(v.y), bfbits(v.z), bfbits(v.w));
}

// ---------------- MFMA bf16 GEMM (pre-cast inputs): C = A @ B^T ----------
// 128x128 block, 4 waves, each wave 64x64 = 4x4 tiles of 16x16, KT=32.
// Row-major LDS, pad 32->40 (round-8 known-good).
__global__ __launch_bounds__(256) void gemm_mfma(
    const unsigned short* __restrict__ A, int lda,
    const unsigned short* __restrict__ B, int ldb,
    float* __restrict__ C, int ldc, int K)
{
    __shared__ unsigned short sA[128][40];
    __shared__ unsigned short sB[128][40];
    const int tid = threadIdx.x;
    const int lane = tid & 63, wave = tid >> 6;
    const int row0 = blockIdx.y * 128, col0 = blockIdx.x * 128;
    const int wm = (wave & 1) << 6, wn = (wave >> 1) << 6;
    const int m = lane & 15;
    const int ko = (lane >> 4) << 3;

    f32x4 acc[4][4];
    const f32x4 zero = {0.f, 0.f, 0.f, 0.f};
#pragma unroll
    for (int i = 0; i < 4; ++i)
#pragma unroll
        for (int j = 0; j < 4; ++j) acc[i][j] = zero;

    for (int k0 = 0; k0 < K; k0 += 32) {
#pragma unroll
        for (int c = 0; c < 2; ++c) {
            int idx = tid + (c << 8);          // 0..511
            int r = idx >> 2;                  // 0..127
            int col8 = (idx & 3) << 3;         // 0,8,16,24
            *(short8*)&sA[r][col8] = *(const short8*)(A + (long)(row0 + r) * lda + k0 + col8);
            *(short8*)&sB[r][col8] = *(const short8*)(B + (long)(col0 + r) * ldb + k0 + col8);
        }
        __syncthreads();

        short8 af[4];
#pragma unroll
        for (int i = 0; i < 4; ++i)
            af[i] = *(const short8*)&sA[wm + i * 16 + m][ko];
#pragma unroll
        for (int j = 0; j < 4; ++j) {
            short8 bf = *(const short8*)&sB[wn + j * 16 + m][ko];
#pragma unroll
            for (int i = 0; i < 4; ++i)
                acc[i][j] = __builtin_amdgcn_mfma_f32_16x16x32_bf16(af[i], bf, acc[i][j], 0, 0, 0);
        }
        __syncthreads();
    }

    const int cr = (lane >> 4) << 2;
#pragma unroll
    for (int i = 0; i < 4; ++i) {
#pragma unroll
        for (int j = 0; j < 4; ++j) {
            int gr = row0 + wm + i * 16 + cr;
            int gc = col0 + wn + j * 16 + m;
#pragma unroll
            for (int r = 0; r < 4; ++r)
                C[(long)(gr + r) * ldc + gc] = acc[i][j][r];
        }
    }
}

// ------- 64x64-tile bf16 GEMM (pre-cast inputs), round-9 known-good -------
// 256 threads = 4 waves; wave w: rows [w*16, w*16+16) x 64 cols.
__global__ __launch_bounds__(256) void gemm_b64(
    const unsigned short* __restrict__ A, int lda,
    const unsigned short* __restrict__ B, int ldb,
    float* __restrict__ C, int ldc, int K)
{
    __shared__ unsigned short sA[64][40];
    __shared__ unsigned short sB[64][40];
    const int tid = threadIdx.x;
    const int lane = tid & 63, wave = tid >> 6;
    const int row0 = blockIdx.y * 64, col0 = blockIdx.x * 64;
    const int m = lane & 15;
    const int ko = (lane >> 4) << 3;

    f32x4 acc[4];
    const f32x4 zero = {0.f, 0.f, 0.f, 0.f};
#pragma unroll
    for (int j = 0; j < 4; ++j) acc[j] = zero;

    for (int k0 = 0; k0 < K; k0 += 32) {
        int r = tid >> 2;                  // 0..63
        int c8 = (tid & 3) << 3;           // 0,8,16,24
        *(short8*)&sA[r][c8] = *(const short8*)(A + (long)(row0 + r) * lda + k0 + c8);
        *(short8*)&sB[r][c8] = *(const short8*)(B + (long)(col0 + r) * ldb + k0 + c8);
        __syncthreads();

        short8 af = *(const short8*)&sA[(wave << 4) + m][ko];
#pragma unroll
        for (int j = 0; j < 4; ++j) {
            short8 bf = *(const short8*)&sB[j * 16 + m][ko];
            acc[j] = __builtin_amdgcn_mfma_f32_16x16x32_bf16(af, bf, acc[j], 0, 0, 0);
        }
        __syncthreads();
    }

    const int cr = (lane >> 4) << 2;
    const int gr = row0 + (wave << 4) + cr;
#pragma unroll
    for (int j = 0; j < 4; ++j) {
        int gc = col0 + j * 16 + m;
#pragma unroll
        for (int r = 0; r < 4; ++r)
            C[(long)(gr + r) * ldc + gc] = acc[j][r];
    }
}

// ------- small-K MFMA GEMM, 64x64 tiles, fp32 inputs cast on the fly ------
enum { ME_PART = 0, ME_SOFTPLUS = 1 };

template <int EPI>
__global__ __launch_bounds__(256) void gemm_s64(
    const float* __restrict__ A, int lda,
    const float* __restrict__ B, int ldb,
    float* __restrict__ C, int ldc,
    const float* __restrict__ bias,
    int N, int kslice, long partStride)
{
    __shared__ unsigned short sA[64][40];
    __shared__ unsigned short sB[64][40];
    const int tid = threadIdx.x;
    const int lane = tid & 63, wave = tid >> 6;
    const int row0 = blockIdx.y * 64, col0 = blockIdx.x * 64;
    const int m = lane & 15;
    const int ko = (lane >> 4) << 3;
    const int kbeg = blockIdx.z * kslice;
    const int kend = kbeg + kslice;

    f32x4 acc[4];
    const f32x4 zero = {0.f, 0.f, 0.f, 0.f};
#pragma unroll
    for (int j = 0; j < 4; ++j) acc[j] = zero;

    for (int k0 = kbeg; k0 < kend; k0 += 32) {
#pragma unroll
        for (int c = 0; c < 2; ++c) {
            int idx = tid + (c << 8);         // 0..511
            int r = idx >> 3;                 // 0..63
            int c4 = (idx & 7) << 2;          // 0,4,..,28
            float4 v = *(const float4*)(A + (long)(row0 + r) * lda + k0 + c4);
            *(ushort4*)&sA[r][c4] = make_ushort4(bfbits(v.x), bfbits(v.y), bfbits(v.z), bfbits(v.w));
            int gr = col0 + r;
            float4 w = make_float4(0.f, 0.f, 0.f, 0.f);
            if (gr < N) w = *(const float4*)(B + (long)gr * ldb + k0 + c4);
            *(ushort4*)&sB[r][c4] = make_ushort4(bfbits(w.x), bfbits(w.y), bfbits(w.z), bfbits(w.w));
        }
        __syncthreads();

        short8 af = *(const short8*)&sA[(wave << 4) + m][ko];
#pragma unroll
        for (int j = 0; j < 4; ++j) {
            short8 bf = *(const short8*)&sB[j * 16 + m][ko];
            acc[j] = __builtin_amdgcn_mfma_f32_16x16x32_bf16(af, bf, acc[j], 0, 0, 0);
        }
        __syncthreads();
    }

    const int cr = (lane >> 4) << 2;
    const int gr = row0 + (wave << 4) + cr;
    float* Cp = C + (long)blockIdx.z * partStride;
#pragma unroll
    for (int j = 0; j < 4; ++j) {
        int gc = col0 + j * 16 + m;
        if (gc >= N) continue;
#pragma unroll
        for (int r = 0; r < 4; ++r) {
            float v = acc[j][r];
            if (EPI == ME_SOFTPLUS) {
                v += bias[gc];
                v = (v > 20.f) ? v : log1pf(__expf(v));
            }
            Cp[(long)(gr + r) * ldc + gc] = v;
        }
    }
}

// ---------------- split-K partial reduction: O = sum_s P[s] ----------------
__global__ __launch_bounds__(256) void reduce_part(
    const float* __restrict__ P, float* __restrict__ O, int n)
{
    int i = (blockIdx.x * 256 + threadIdx.x) * 4;
    if (i >= n) return;
    float4 s = *(const float4*)(P + i);
#pragma unroll
    for (int k = 1; k < SK_; ++k) {
        float4 v = *(const float4*)(P + (long)k * n + i);
        s.x += v.x; s.y += v.y; s.z += v.z; s.w += v.w;
    }
    *(float4*)(O + i) = s;
}

// ---------------- causal depthwise conv(4) + bias + SiLU ----------------
__global__ __launch_bounds__(256) void conv_silu(
    const float* __restrict__ xz, const float* __restrict__ w,
    const float* __restrict__ bc, float* __restrict__ U)
{
    int idx = blockIdx.x * 256 + threadIdx.x;       // (b*L + t)*DI + d
    if (idx >= B_ * L_ * DI_) return;
    int d = idx & (DI_ - 1);
    int bt = idx >> 11;
    int t = bt & (L_ - 1);
    float s = bc[d];
#pragma unroll
    for (int j = 0; j < 4; ++j) {
        int tt = t - 3 + j;
        if (tt >= 0)
            s += w[d * 4 + j] * xz[((long)(bt - t + tt)) * (2 * DI_) + d];
    }
    U[idx] = s / (1.f + __expf(-s));                // silu
}

// ---------------- Pass A: per-chunk h_end + dt-sum only --------------------
__global__ __launch_bounds__(256) void scan_head(
    const float* __restrict__ U, const float* __restrict__ DT,
    const float* __restrict__ XDBL, const float* __restrict__ A_log,
    float* __restrict__ HEND, float* __restrict__ SDT)
{
    const int d = blockIdx.x * 256 + threadIdx.x;
    const int chunk = blockIdx.y;
    const int b = blockIdx.z;
    const int channel = b * DI_ + d;
    const long t0 = (long)b * L_ + chunk * CL_;

    float An[NS_], h[NS_];
#pragma unroll
    for (int n = 0; n < NS_; ++n) {
        An[n] = -__expf(A_log[d * NS_ + n]);
        h[n] = 0.f;
    }
    float sum_dt = 0.f;
    __shared__ float sB[8][NS_];

    for (int tt0 = 0; tt0 < CL_; tt0 += 8) {
        const long bt0 = t0 + tt0;
        if (threadIdx.x < 128) {
            int i = threadIdx.x >> 4, j = threadIdx.x & 15;
            sB[i][j] = XDBL[(bt0 + i) * XPN_ + DTR_ + j];
        }
        __syncthreads();
        float u8[8], dt8[8];
#pragma unroll
        for (int i = 0; i < 8; ++i) u8[i] = U[(bt0 + i) * DI_ + d];
#pragma unroll
        for (int i = 0; i < 8; ++i) dt8[i] = DT[(bt0 + i) * DI_ + d];
#pragma unroll
        for (int i = 0; i < 8; ++i) {
            const float dt = dt8[i];
            sum_dt += dt;
            const float du = dt * u8[i];
#pragma unroll
            for (int n = 0; n < NS_; ++n)
                h[n] = __expf(An[n] * dt) * h[n] + du * sB[i][n];
        }
        __syncthreads();
    }
#pragma unroll
    for (int n = 0; n < NS_; ++n)
        HEND[(chunk * NS_ + n) * NCH_ + channel] = h[n];
    SDT[chunk * NCH_ + channel] = sum_dt;
}

// ---------------- Pass B: combine chunk states (in-place) ----------------
__global__ __launch_bounds__(256) void scan_mid(
    const float* __restrict__ SDT, const float* __restrict__ A_log,
    float* __restrict__ HST)
{
    const int channel = blockIdx.x * 256 + threadIdx.x;
    const int d = channel & (DI_ - 1);
    float An[NS_], h0[NS_];
#pragma unroll
    for (int n = 0; n < NS_; ++n) {
        An[n] = -__expf(A_log[d * NS_ + n]);
        h0[n] = 0.f;
    }
    for (int c = 0; c < CH_; ++c) {
        float he[NS_];
#pragma unroll
        for (int n = 0; n < NS_; ++n) {
            he[n] = HST[(c * NS_ + n) * NCH_ + channel];
            HST[(c * NS_ + n) * NCH_ + channel] = h0[n];
        }
        if (c < CH_ - 1) {
            const float S = SDT[c * NCH_ + channel];
#pragma unroll
            for (int n = 0; n < NS_; ++n)
                h0[n] = __expf(An[n] * S) * h0[n] + he[n];
        }
    }
}

// ---------------- Pass C: full recurrence from h_start + gate --------------
// Emits y directly as bf16 into the dead xb-quarter of XZ:
//   YOUT = (ushort*)XZ, row stride 4*DI ushorts (first 4KB of each 16KB row).
// No overlap with the z-half it reads (bytes 8-16KB of each row); xb half is
// dead after conv, so no cross-block hazard.
__global__ __launch_bounds__(256) void scan_tail(
    const float* __restrict__ U, const float* __restrict__ DT,
    const float* __restrict__ XDBL, const float* __restrict__ A_log,
    const float* __restrict__ Dp, const float* __restrict__ HST,
    float* __restrict__ XZ)
{
    const int d = blockIdx.x * 256 + threadIdx.x;
    const int chunk = blockIdx.y;
    const int b = blockIdx.z;
    const int channel = b * DI_ + d;
    const long t0 = (long)b * L_ + chunk * CL_;
    unsigned short* YOUT = (unsigned short*)XZ;

    float An[NS_], h[NS_];
#pragma unroll
    for (int n = 0; n < NS_; ++n) {
        An[n] = -__expf(A_log[d * NS_ + n]);
        h[n] = HST[(chunk * NS_ + n) * NCH_ + channel];
    }
    const float Dd = Dp[d];
    __shared__ float sB[8][NS_], sC[8][NS_];

    for (int tt0 = 0; tt0 < CL_; tt0 += 8) {
        const long bt0 = t0 + tt0;
        {
            int i = threadIdx.x >> 5, j = threadIdx.x & 31;
            float v = XDBL[(bt0 + i) * XPN_ + DTR_ + j];
            if (j < NS_) sB[i][j] = v; else sC[i][j - NS_] = v;
        }
        __syncthreads();
        float u8[8], dt8[8], z8[8];
        unsigned short y8[8];
#pragma unroll
        for (int i = 0; i < 8; ++i) u8[i] = U[(bt0 + i) * DI_ + d];
#pragma unroll
        for (int i = 0; i < 8; ++i) dt8[i] = DT[(bt0 + i) * DI_ + d];
#pragma unroll
        for (int i = 0; i < 8; ++i) z8[i] = XZ[(bt0 + i) * (2 * DI_) + DI_ + d];
#pragma unroll
        for (int i = 0; i < 8; ++i) {
            const float dt = dt8[i];
            const float du = dt * u8[i];
            float y = 0.f;
#pragma unroll
            for (int n = 0; n < NS_; ++n) {
                h[n] = __expf(An[n] * dt) * h[n] + du * sB[i][n];
                y += h[n] * sC[i][n];
            }
            y += u8[i] * Dd;
            const float z = z8[i];
            y8[i] = bfbits(y * (z / (1.f + __expf(-z))));
        }
#pragma unroll
        for (int i = 0; i < 8; ++i) YOUT[(bt0 + i) * (4 * DI_) + d] = y8[i];
        __syncthreads();
    }
}

extern "C" void kernel_launch(void* const* d_in, const int* in_sizes, int n_in,
                              void* d_out, int out_size, void* d_ws, size_t ws_size,
                              hipStream_t stream)
{
    const float* x        = (const float*)d_in[0];
    const float* in_proj  = (const float*)d_in[1];
    const float* conv_w   = (const float*)d_in[2];
    const float* conv_b   = (const float*)d_in[3];
    const float* x_proj   = (const float*)d_in[4];
    const float* dt_proj  = (const float*)d_in[5];
    const float* dt_projb = (const float*)d_in[6];
    const float* A_log    = (const float*)d_in[7];
    const float* Dp       = (const float*)d_in[8];
    const float* out_proj = (const float*)d_in[9];

    const int M = B_ * L_;                       // 4096
    float* XZ   = (float*)d_ws;                  // [M, 2*DI]   67 MB
    float* U    = XZ + (size_t)M * 2 * DI_;      // [M, DI]     33.5 MB
    float* XDBL = U + (size_t)M * DI_;           // [M, 160]    2.6 MB
    float* DT   = XDBL + (size_t)M * XPN_;       // [M, DI]     33.5 MB
    float* SDT  = DT + (size_t)M * DI_;          // [CH][NCH]   0.5 MB
    float* HEND = (float*)d_out;                 // 8.4 MB in d_out (dead until GEMM4)

    // --- overlays (disjoint lifetimes) ---
    const int NX = M * DM_;
    const int NO = DM_ * DI_;
    unsigned short* XB = (unsigned short*)U;          // x bf16; dead before conv writes U
    unsigned short* WB = (unsigned short*)DT;         // in_proj bf16; dead after GEMM1
    float* PART = DT;                                 // [SK_][M][160] = 21 MB, dead after reduce
    unsigned short* YOUT = (unsigned short*)XZ;       // y bf16 in xb-quarter (stride 4*DI)
    unsigned short* OB = (unsigned short*)DT;         // out_proj bf16; DT dead after scan_tail

    // 1) cast x and in_proj to bf16 (single fused launch)
    cast_pair<<<2 * NX / 1024, 256, 0, stream>>>(x, XB, in_proj, WB, NX);

    // 2) xz = x @ in_proj^T  (MFMA bf16)  [4096 x 4096], K=1024
    gemm_mfma<<<dim3(32, 32), 256, 0, stream>>>(
        XB, DM_, WB, DM_, XZ, 2 * DI_, DM_);

    // 3) u = silu(conv(xb) + b)
    conv_silu<<<(M * DI_ + 255) / 256, 256, 0, stream>>>(XZ, conv_w, conv_b, U);

    // 4) x_dbl = u @ x_proj^T  [4096 x 160], K=2048; split-K x8, 64x64 tiles
    gemm_s64<ME_PART><<<dim3(3, 64, SK_), 256, 0, stream>>>(
        U, DI_, x_proj, DI_, PART, XPN_, nullptr, XPN_, 2048 / SK_, (long)M * XPN_);
    reduce_part<<<(M * XPN_) / 1024, 256, 0, stream>>>(PART, XDBL, M * XPN_);

    // 5) dt = softplus(x_dbl[:, :128] @ dt_proj^T + b)  [4096 x 2048], K=128
    gemm_s64<ME_SOFTPLUS><<<dim3(32, 64, 1), 256, 0, stream>>>(
        XDBL, XPN_, dt_proj, DTR_, DT, DI_, dt_projb, DI_, DTR_, 0);

    // 6) chunked selective scan; tail writes y as bf16 into YOUT
    scan_head<<<dim3(8, CH_, B_), 256, 0, stream>>>(U, DT, XDBL, A_log, HEND, SDT);
    scan_mid<<<NCH_ / 256, 256, 0, stream>>>(SDT, A_log, HEND);
    scan_tail<<<dim3(8, CH_, B_), 256, 0, stream>>>(U, DT, XDBL, A_log, Dp, HEND, XZ);

    // 7) cast out_proj to bf16 (DT dead now)
    cast_flat<<<NO / 1024, 256, 0, stream>>>(out_proj, OB, NO);

    // 8) out = y @ out_proj^T  (64x64 bf16)  [4096 x 1024], K=2048
    gemm_b64<<<dim3(16, 64), 256, 0, stream>>>(
        YOUT, 4 * DI_, OB, DI_, (float*)d_out, DM_, DI_);
}